// Round 5
// baseline (869.805 us; speedup 1.0000x reference)
//
#include <hip/hip_runtime.h>

#define BATCH 16
#define N_RIGIDS 8192
#define N_RES 2048
#define C_FRAME 384
#define C_S 384
#define N_AA 21
#define EPS 1e-5f

#define N_RIG_TOT (BATCH * N_RIGIDS)   // 131072
#define N_ROWS    (BATCH * N_RES)      // 32768
#define CAP 32                         // max rigids per residue (lambda=4)
#define ZROW 32                        // floats per bucket slot row (128 B)

// ws layout (float offsets)
#define CS_OFF  0                      // [21] colsum(Gc)      (atomic, zeroed)
#define B2_OFF  64                     // [21] bias2           (atomic, zeroed)
#define GCT_OFF 1024                   // [21][384] GcT (transposed Gc)
#define WOT_OFF 10240                  // [21][384] WoT (transposed W_out)
#define HIST_OFF 20480                 // int[32768]
#define ZB_OFF  65536                  // [32768*32*32] bucket contributions

// ---- k0: build GcT/WoT + colsum/bias2. t -> (f = t/21, a = t%21). ----
__global__ void __launch_bounds__(256) precompute(const float* __restrict__ W_su,
                                                  const float* __restrict__ W_out,
                                                  const float* __restrict__ ln_g,
                                                  const float* __restrict__ ln_b,
                                                  const float* __restrict__ b_su,
                                                  float* __restrict__ ws) {
    __shared__ float binc[N_AA], binb[N_AA];
    int tid = threadIdx.x;
    if (tid < N_AA) { binc[tid] = 0.f; binb[tid] = 0.f; }
    __syncthreads();
    int t = blockIdx.x * 256 + tid;
    if (t < C_FRAME * N_AA) {
        int f = t / N_AA, a = t - f * N_AA;
        const float4* wr = (const float4*)(W_su + (size_t)f * C_S);
        float wc = 0.f;
        for (int q = 0; q < C_S / 4; ++q) {
            float4 v = wr[q];
            int s = 4 * q;
            wc += v.x * W_out[(s + 0) * N_AA + a];
            wc += v.y * W_out[(s + 1) * N_AA + a];
            wc += v.z * W_out[(s + 2) * N_AA + a];
            wc += v.w * W_out[(s + 3) * N_AA + a];
        }
        float g = ln_g[f] * wc;
        float wo = W_out[f * N_AA + a];
        ws[GCT_OFF + a * C_FRAME + f] = g;
        ws[WOT_OFF + a * C_FRAME + f] = wo;
        atomicAdd(&binc[a], g);
        atomicAdd(&binb[a], ln_b[f] * wc + b_su[f] * wo);
    }
    __syncthreads();
    if (tid < N_AA) {
        atomicAdd(ws + CS_OFF + tid, binc[tid]);
        atomicAdd(ws + B2_OFF + tid, binb[tid]);
    }
}

// ---- k1: 8 lanes per rigid row; lane j computes 3 outputs via GcT float4s ----
__global__ void __launch_bounds__(256, 4) zcompute(const float* __restrict__ embed,
                                                   const int* __restrict__ idx,
                                                   const float* __restrict__ mask,
                                                   const float* __restrict__ ws,
                                                   float* __restrict__ zb,
                                                   int* __restrict__ hist) {
    int T = blockIdx.x * 256 + threadIdx.x;
    int row = T >> 3, j = T & 7;
    int a0 = (j < 7) ? 3 * j : 18;
    const float4* xr = (const float4*)(embed + (size_t)row * C_FRAME);
    const float4* g0 = (const float4*)(ws + GCT_OFF + (a0 + 0) * C_FRAME);
    const float4* g1 = (const float4*)(ws + GCT_OFF + (a0 + 1) * C_FRAME);
    const float4* g2 = (const float4*)(ws + GCT_OFF + (a0 + 2) * C_FRAME);
    float acc0 = 0.f, acc1 = 0.f, acc2 = 0.f, sum = 0.f, ssq = 0.f;
#pragma unroll 4
    for (int q = 0; q < C_FRAME / 4; ++q) {
        float4 x = xr[q];
        sum += x.x + x.y + x.z + x.w;
        ssq += x.x * x.x + x.y * x.y + x.z * x.z + x.w * x.w;
        float4 a = g0[q], b = g1[q], c = g2[q];
        acc0 += x.x * a.x + x.y * a.y + x.z * a.z + x.w * a.w;
        acc1 += x.x * b.x + x.y * b.y + x.z * b.z + x.w * b.w;
        acc2 += x.x * c.x + x.y * c.y + x.z * c.z + x.w * c.w;
    }
    float mu  = sum * (1.f / C_FRAME);
    float var = ssq * (1.f / C_FRAME) - mu * mu;
    float inv = rsqrtf(var + EPS);
    float m = mask[row];
    int g = ((row >> 13) << 11) + idx[row];
    int slotr = 0;
    if (j == 0) slotr = atomicAdd(hist + g, 1);
    int lane = threadIdx.x & 63;
    int slot = __shfl(slotr, lane & ~7);
    if (j < 7 && slot < CAP) {
        const float* cs = ws + CS_OFF;
        const float* b2 = ws + B2_OFF;
        float* zr = zb + ((size_t)g * CAP + slot) * ZROW + a0;
        zr[0] = m * (inv * (acc0 - mu * cs[a0 + 0]) + b2[a0 + 0]);
        zr[1] = m * (inv * (acc1 - mu * cs[a0 + 1]) + b2[a0 + 1]);
        zr[2] = m * (inv * (acc2 - mu * cs[a0 + 2]) + b2[a0 + 2]);
    }
}

// ---- k2: 8 lanes per residue row; base proj via WoT + contiguous bucket sum ----
__global__ void __launch_bounds__(256, 4) final_gather(const float* __restrict__ out_in,
                                                       const float* __restrict__ b_out,
                                                       const float* __restrict__ ws,
                                                       const float* __restrict__ zb,
                                                       const int* __restrict__ hist,
                                                       float* __restrict__ logits) {
    int T = blockIdx.x * 256 + threadIdx.x;
    int row = T >> 3, j = T & 7;
    int a0 = (j < 7) ? 3 * j : 18;
    const float4* xr = (const float4*)(out_in + (size_t)row * C_S);
    const float4* w0 = (const float4*)(ws + WOT_OFF + (a0 + 0) * C_FRAME);
    const float4* w1 = (const float4*)(ws + WOT_OFF + (a0 + 1) * C_FRAME);
    const float4* w2 = (const float4*)(ws + WOT_OFF + (a0 + 2) * C_FRAME);
    float acc0 = b_out[a0 + 0], acc1 = b_out[a0 + 1], acc2 = b_out[a0 + 2];
#pragma unroll 4
    for (int q = 0; q < C_S / 4; ++q) {
        float4 x = xr[q];
        float4 a = w0[q], b = w1[q], c = w2[q];
        acc0 += x.x * a.x + x.y * a.y + x.z * a.z + x.w * a.w;
        acc1 += x.x * b.x + x.y * b.y + x.z * b.z + x.w * b.w;
        acc2 += x.x * c.x + x.y * c.y + x.z * c.z + x.w * c.w;
    }
    int cnt = hist[row];
    if (cnt > CAP) cnt = CAP;
    const float* zbase = zb + (size_t)row * CAP * ZROW + a0;
    for (int i = 0; i < cnt; ++i) {
        const float* zr = zbase + i * ZROW;
        acc0 += zr[0]; acc1 += zr[1]; acc2 += zr[2];
    }
    if (j < 7) {
        float* o = logits + (size_t)row * N_AA + a0;
        o[0] = acc0; o[1] = acc1; o[2] = acc2;
    }
}

extern "C" void kernel_launch(void* const* d_in, const int* in_sizes, int n_in,
                              void* d_out, int out_size, void* d_ws, size_t ws_size,
                              hipStream_t stream) {
    const float* embed  = (const float*)d_in[0];
    const int*   idx    = (const int*)d_in[1];
    const float* mask   = (const float*)d_in[2];
    const float* out_in = (const float*)d_in[3];
    const float* ln_g   = (const float*)d_in[4];
    const float* ln_b   = (const float*)d_in[5];
    const float* W_su   = (const float*)d_in[6];
    const float* b_su   = (const float*)d_in[7];
    const float* W_out  = (const float*)d_in[8];
    const float* b_out  = (const float*)d_in[9];
    float* logits = (float*)d_out;
    float* ws = (float*)d_ws;
    float* zb   = ws + ZB_OFF;
    int*   hist = (int*)(ws + HIST_OFF);

    // zero cs/b2 bins + hist (GcT/WoT fully overwritten by k0)
    hipMemsetAsync(ws, 0, (HIST_OFF + N_ROWS) * sizeof(float), stream);
    hipLaunchKernelGGL(precompute, dim3((C_FRAME * N_AA + 255) / 256), dim3(256), 0, stream,
                       W_su, W_out, ln_g, ln_b, b_su, ws);
    hipLaunchKernelGGL(zcompute, dim3(N_RIG_TOT * 8 / 256), dim3(256), 0, stream,
                       embed, idx, mask, ws, zb, hist);
    hipLaunchKernelGGL(final_gather, dim3(N_ROWS * 8 / 256), dim3(256), 0, stream,
                       out_in, b_out, ws, zb, hist, logits);
}